// Round 1
// baseline (3958.067 us; speedup 1.0000x reference)
//
#include <hip/hip_runtime.h>
#include <cmath>

#define N_NODES 100000
#define N_EDGES 1600000
#define IN_F 48
#define HID_F 16
#define OUT_F 60

// ---------------- Layer-1 node transform: Y = x@W1_rel, P = x@W1_root + b1 ----
__global__ __launch_bounds__(256) void k1_lin48(
    const float* __restrict__ x, const float* __restrict__ Wrel,
    const float* __restrict__ b, const float* __restrict__ Wroot,
    float* __restrict__ Y, float* __restrict__ P)
{
    __shared__ float sWrel[IN_F * HID_F];
    __shared__ float sWroot[IN_F * HID_F];
    __shared__ float sb[HID_F];
    for (int i = threadIdx.x; i < IN_F * HID_F; i += 256) {
        sWrel[i]  = Wrel[i];
        sWroot[i] = Wroot[i];
    }
    if (threadIdx.x < HID_F) sb[threadIdx.x] = b[threadIdx.x];
    __syncthreads();

    int n = blockIdx.x * 256 + threadIdx.x;
    if (n >= N_NODES) return;

    float xv[IN_F];
    const float4* xr = reinterpret_cast<const float4*>(x + (size_t)n * IN_F);
    #pragma unroll
    for (int i = 0; i < IN_F / 4; ++i) {
        float4 t = xr[i];
        xv[4*i+0] = t.x; xv[4*i+1] = t.y; xv[4*i+2] = t.z; xv[4*i+3] = t.w;
    }

    float accR[HID_F], accT[HID_F];
    #pragma unroll
    for (int f = 0; f < HID_F; ++f) { accR[f] = 0.0f; accT[f] = sb[f]; }

    #pragma unroll 6
    for (int k = 0; k < IN_F; ++k) {
        float xk = xv[k];
        #pragma unroll
        for (int f = 0; f < HID_F; ++f) {
            accR[f] = fmaf(xk, sWrel[k*HID_F + f], accR[f]);
            accT[f] = fmaf(xk, sWroot[k*HID_F + f], accT[f]);
        }
    }

    float4* yr = reinterpret_cast<float4*>(Y + (size_t)n * HID_F);
    float4* pr = reinterpret_cast<float4*>(P + (size_t)n * HID_F);
    #pragma unroll
    for (int q = 0; q < HID_F / 4; ++q) {
        yr[q] = make_float4(accR[4*q], accR[4*q+1], accR[4*q+2], accR[4*q+3]);
        pr[q] = make_float4(accT[4*q], accT[4*q+1], accT[4*q+2], accT[4*q+3]);
    }
}

// ---------------- Edge scatter: P[dst] += Y[src]  (16 f32 atomics / edge) -----
__global__ __launch_bounds__(256) void k_edge_scatter(
    const int* __restrict__ src, const int* __restrict__ dst,
    const float* __restrict__ Y, float* __restrict__ P)
{
    int e = blockIdx.x * 256 + threadIdx.x;
    if (e >= N_EDGES) return;
    int s = src[e];
    int d = dst[e];
    const float4* yr = reinterpret_cast<const float4*>(Y + (size_t)s * HID_F);
    float4 v0 = yr[0], v1 = yr[1], v2 = yr[2], v3 = yr[3];
    float* pr = P + (size_t)d * HID_F;
    atomicAdd(pr + 0,  v0.x); atomicAdd(pr + 1,  v0.y);
    atomicAdd(pr + 2,  v0.z); atomicAdd(pr + 3,  v0.w);
    atomicAdd(pr + 4,  v1.x); atomicAdd(pr + 5,  v1.y);
    atomicAdd(pr + 6,  v1.z); atomicAdd(pr + 7,  v1.w);
    atomicAdd(pr + 8,  v2.x); atomicAdd(pr + 9,  v2.y);
    atomicAdd(pr + 10, v2.z); atomicAdd(pr + 11, v2.w);
    atomicAdd(pr + 12, v3.x); atomicAdd(pr + 13, v3.y);
    atomicAdd(pr + 14, v3.z); atomicAdd(pr + 15, v3.w);
}

// -------- Layer-2 node transform (in place): h=tanh(P); Y=h@Wrel; P=h@Wroot+b --
__global__ __launch_bounds__(256) void k3_lin16(
    float* __restrict__ Y, float* __restrict__ P,
    const float* __restrict__ Wrel, const float* __restrict__ b,
    const float* __restrict__ Wroot)
{
    __shared__ float sWrel[HID_F * HID_F];
    __shared__ float sWroot[HID_F * HID_F];
    __shared__ float sb[HID_F];
    if (threadIdx.x < HID_F * HID_F) {
        sWrel[threadIdx.x]  = Wrel[threadIdx.x];
        sWroot[threadIdx.x] = Wroot[threadIdx.x];
    }
    if (threadIdx.x < HID_F) sb[threadIdx.x] = b[threadIdx.x];
    __syncthreads();

    int n = blockIdx.x * 256 + threadIdx.x;
    if (n >= N_NODES) return;

    float h[HID_F];
    float4* pr = reinterpret_cast<float4*>(P + (size_t)n * HID_F);
    #pragma unroll
    for (int q = 0; q < HID_F / 4; ++q) {
        float4 t = pr[q];
        h[4*q+0] = tanhf(t.x); h[4*q+1] = tanhf(t.y);
        h[4*q+2] = tanhf(t.z); h[4*q+3] = tanhf(t.w);
    }

    float accR[HID_F], accT[HID_F];
    #pragma unroll
    for (int f = 0; f < HID_F; ++f) { accR[f] = 0.0f; accT[f] = sb[f]; }

    #pragma unroll
    for (int k = 0; k < HID_F; ++k) {
        float hk = h[k];
        #pragma unroll
        for (int f = 0; f < HID_F; ++f) {
            accR[f] = fmaf(hk, sWrel[k*HID_F + f], accR[f]);
            accT[f] = fmaf(hk, sWroot[k*HID_F + f], accT[f]);
        }
    }

    float4* yr = reinterpret_cast<float4*>(Y + (size_t)n * HID_F);
    #pragma unroll
    for (int q = 0; q < HID_F / 4; ++q) {
        yr[q] = make_float4(accR[4*q], accR[4*q+1], accR[4*q+2], accR[4*q+3]);
        pr[q] = make_float4(accT[4*q], accT[4*q+1], accT[4*q+2], accT[4*q+3]);
    }
}

// -------- Layer-3 prep: Y = tanh(P) (=h2), P = 0 (agg accumulator) ------------
__global__ __launch_bounds__(256) void k5_tanh_zero(
    float* __restrict__ P, float* __restrict__ Y)
{
    int n = blockIdx.x * 256 + threadIdx.x;
    if (n >= N_NODES) return;
    float4* pr = reinterpret_cast<float4*>(P + (size_t)n * HID_F);
    float4* yr = reinterpret_cast<float4*>(Y + (size_t)n * HID_F);
    #pragma unroll
    for (int q = 0; q < HID_F / 4; ++q) {
        float4 t = pr[q];
        yr[q] = make_float4(tanhf(t.x), tanhf(t.y), tanhf(t.z), tanhf(t.w));
        pr[q] = make_float4(0.f, 0.f, 0.f, 0.f);
    }
}

// -------- Output: out = P(agg)@W2_rel + b2 + Y(h2)@W2_root --------------------
__global__ __launch_bounds__(256) void k7_out(
    const float* __restrict__ P, const float* __restrict__ Y,
    const float* __restrict__ Wrel, const float* __restrict__ b,
    const float* __restrict__ Wroot, float* __restrict__ out)
{
    __shared__ float sWrel[HID_F * OUT_F];
    __shared__ float sWroot[HID_F * OUT_F];
    __shared__ float sb[OUT_F];
    for (int i = threadIdx.x; i < HID_F * OUT_F; i += 256) {
        sWrel[i]  = Wrel[i];
        sWroot[i] = Wroot[i];
    }
    if (threadIdx.x < OUT_F) sb[threadIdx.x] = b[threadIdx.x];
    __syncthreads();

    int n = blockIdx.x * 256 + threadIdx.x;
    if (n >= N_NODES) return;

    float agg[HID_F], h[HID_F];
    const float4* pr = reinterpret_cast<const float4*>(P + (size_t)n * HID_F);
    const float4* yr = reinterpret_cast<const float4*>(Y + (size_t)n * HID_F);
    #pragma unroll
    for (int q = 0; q < HID_F / 4; ++q) {
        float4 a = pr[q], hh = yr[q];
        agg[4*q+0] = a.x; agg[4*q+1] = a.y; agg[4*q+2] = a.z; agg[4*q+3] = a.w;
        h[4*q+0] = hh.x;  h[4*q+1] = hh.y;  h[4*q+2] = hh.z;  h[4*q+3] = hh.w;
    }

    float acc[OUT_F];
    #pragma unroll
    for (int j = 0; j < OUT_F; ++j) acc[j] = sb[j];

    #pragma unroll 2
    for (int f = 0; f < HID_F; ++f) {
        float a = agg[f], hh = h[f];
        #pragma unroll
        for (int j = 0; j < OUT_F; ++j) {
            acc[j] = fmaf(a,  sWrel[f*OUT_F + j], acc[j]);
            acc[j] = fmaf(hh, sWroot[f*OUT_F + j], acc[j]);
        }
    }

    float4* orow = reinterpret_cast<float4*>(out + (size_t)n * OUT_F);
    #pragma unroll
    for (int q = 0; q < OUT_F / 4; ++q) {
        orow[q] = make_float4(acc[4*q], acc[4*q+1], acc[4*q+2], acc[4*q+3]);
    }
}

extern "C" void kernel_launch(void* const* d_in, const int* in_sizes, int n_in,
                              void* d_out, int out_size, void* d_ws, size_t ws_size,
                              hipStream_t stream)
{
    const float* x        = (const float*)d_in[0];
    const int*   ei       = (const int*)d_in[1];
    const float* W1_rel   = (const float*)d_in[2];
    const float* b1       = (const float*)d_in[3];
    const float* W1_root  = (const float*)d_in[4];
    const float* W1b_rel  = (const float*)d_in[5];
    const float* b1b      = (const float*)d_in[6];
    const float* W1b_root = (const float*)d_in[7];
    const float* W2_rel   = (const float*)d_in[8];
    const float* b2       = (const float*)d_in[9];
    const float* W2_root  = (const float*)d_in[10];
    float* out = (float*)d_out;

    const int* src = ei;            // edge_index[0]
    const int* dst = ei + N_EDGES;  // edge_index[1]

    float* Y = (float*)d_ws;                       // [N, 16]
    float* P = Y + (size_t)N_NODES * HID_F;        // [N, 16]

    const int nb_n = (N_NODES + 255) / 256;
    const int nb_e = (N_EDGES + 255) / 256;

    // Layer 1
    k1_lin48<<<nb_n, 256, 0, stream>>>(x, W1_rel, b1, W1_root, Y, P);
    k_edge_scatter<<<nb_e, 256, 0, stream>>>(src, dst, Y, P);
    // Layer 2
    k3_lin16<<<nb_n, 256, 0, stream>>>(Y, P, W1b_rel, b1b, W1b_root);
    k_edge_scatter<<<nb_e, 256, 0, stream>>>(src, dst, Y, P);
    // Layer 3
    k5_tanh_zero<<<nb_n, 256, 0, stream>>>(P, Y);
    k_edge_scatter<<<nb_e, 256, 0, stream>>>(src, dst, Y, P);
    k7_out<<<nb_n, 256, 0, stream>>>(P, Y, W2_rel, b2, W2_root, out);
}

// Round 2
// 376.300 us; speedup vs baseline: 10.5184x; 10.5184x over previous
//
#include <hip/hip_runtime.h>
#include <cmath>

#define N_NODES 100000
#define N_EDGES 1600000
#define IN_F 48
#define HID_F 16
#define OUT_F 60

#define NB_SCAN ((N_NODES + 255) / 256)   // 391 blocks

// ---------------- CSR build ---------------------------------------------------
__global__ __launch_bounds__(256) void k_zero_deg(int* __restrict__ deg)
{
    int i = blockIdx.x * 256 + threadIdx.x;
    if (i < N_NODES) deg[i] = 0;
}

__global__ __launch_bounds__(256) void k_hist(
    const int* __restrict__ dst, int* __restrict__ deg)
{
    int e = blockIdx.x * 256 + threadIdx.x;
    if (e < N_EDGES) atomicAdd(&deg[dst[e]], 1);
}

// Per-block exclusive scan (in place on off[]), block totals to blk_sums.
__global__ __launch_bounds__(256) void k_scan_block(
    int* __restrict__ off, int* __restrict__ blk_sums)
{
    __shared__ int tmp[256];
    int i = blockIdx.x * 256 + threadIdx.x;
    int v = (i < N_NODES) ? off[i] : 0;
    tmp[threadIdx.x] = v;
    __syncthreads();
    #pragma unroll
    for (int ofs = 1; ofs < 256; ofs <<= 1) {
        int add = (threadIdx.x >= ofs) ? tmp[threadIdx.x - ofs] : 0;
        __syncthreads();
        tmp[threadIdx.x] += add;
        __syncthreads();
    }
    if (i < N_NODES) off[i] = tmp[threadIdx.x] - v;          // exclusive
    if (threadIdx.x == 255) blk_sums[blockIdx.x] = tmp[255]; // block total
}

// Single-block exclusive scan of the 391 block sums (512 >= NB_SCAN).
__global__ __launch_bounds__(512) void k_scan_sums(int* __restrict__ blk_sums)
{
    __shared__ int tmp[512];
    int v = (threadIdx.x < NB_SCAN) ? blk_sums[threadIdx.x] : 0;
    tmp[threadIdx.x] = v;
    __syncthreads();
    #pragma unroll
    for (int ofs = 1; ofs < 512; ofs <<= 1) {
        int add = (threadIdx.x >= ofs) ? tmp[threadIdx.x - ofs] : 0;
        __syncthreads();
        tmp[threadIdx.x] += add;
        __syncthreads();
    }
    if (threadIdx.x < NB_SCAN) blk_sums[threadIdx.x] = tmp[threadIdx.x] - v;
}

__global__ __launch_bounds__(256) void k_scan_add(
    int* __restrict__ off, const int* __restrict__ blk_sums)
{
    int i = blockIdx.x * 256 + threadIdx.x;
    if (i < N_NODES) off[i] += blk_sums[blockIdx.x];
}

// Fill CSR. Uses off[] itself as the bump cursor: afterwards off[n] is the END
// of node n's segment (start of node n = end of node n-1, node 0 starts at 0).
__global__ __launch_bounds__(256) void k_fill(
    const int* __restrict__ src, const int* __restrict__ dst,
    int* __restrict__ off_cursor, int* __restrict__ csr_src)
{
    int e = blockIdx.x * 256 + threadIdx.x;
    if (e >= N_EDGES) return;
    int pos = atomicAdd(&off_cursor[dst[e]], 1);
    csr_src[pos] = src[e];
}

// ---------------- Gather: P[n] += sum_{e in in(n)} Y[src[e]] ------------------
// 16 lanes per node; lane = feature index. Coalesced 64B row reads, no atomics.
__global__ __launch_bounds__(256) void k_gather(
    const int* __restrict__ off_end, const int* __restrict__ csr_src,
    const float* __restrict__ Y, float* __restrict__ P)
{
    int t = blockIdx.x * 256 + threadIdx.x;
    int n = t >> 4;
    int lane = t & 15;
    if (n >= N_NODES) return;
    int e0 = (n == 0) ? 0 : off_end[n - 1];
    int e1 = off_end[n];

    float acc0 = 0.f, acc1 = 0.f;
    int e = e0;
    for (; e + 1 < e1; e += 2) {
        int s0 = csr_src[e];
        int s1 = csr_src[e + 1];
        acc0 += Y[(size_t)s0 * HID_F + lane];
        acc1 += Y[(size_t)s1 * HID_F + lane];
    }
    if (e < e1) acc0 += Y[(size_t)csr_src[e] * HID_F + lane];
    P[(size_t)n * HID_F + lane] += acc0 + acc1;
}

// ---------------- Layer-1 node transform: Y = x@W1_rel, P = x@W1_root + b1 ----
__global__ __launch_bounds__(256) void k1_lin48(
    const float* __restrict__ x, const float* __restrict__ Wrel,
    const float* __restrict__ b, const float* __restrict__ Wroot,
    float* __restrict__ Y, float* __restrict__ P)
{
    __shared__ float sWrel[IN_F * HID_F];
    __shared__ float sWroot[IN_F * HID_F];
    __shared__ float sb[HID_F];
    for (int i = threadIdx.x; i < IN_F * HID_F; i += 256) {
        sWrel[i]  = Wrel[i];
        sWroot[i] = Wroot[i];
    }
    if (threadIdx.x < HID_F) sb[threadIdx.x] = b[threadIdx.x];
    __syncthreads();

    int n = blockIdx.x * 256 + threadIdx.x;
    if (n >= N_NODES) return;

    float xv[IN_F];
    const float4* xr = reinterpret_cast<const float4*>(x + (size_t)n * IN_F);
    #pragma unroll
    for (int i = 0; i < IN_F / 4; ++i) {
        float4 t = xr[i];
        xv[4*i+0] = t.x; xv[4*i+1] = t.y; xv[4*i+2] = t.z; xv[4*i+3] = t.w;
    }

    float accR[HID_F], accT[HID_F];
    #pragma unroll
    for (int f = 0; f < HID_F; ++f) { accR[f] = 0.0f; accT[f] = sb[f]; }

    #pragma unroll 6
    for (int k = 0; k < IN_F; ++k) {
        float xk = xv[k];
        #pragma unroll
        for (int f = 0; f < HID_F; ++f) {
            accR[f] = fmaf(xk, sWrel[k*HID_F + f], accR[f]);
            accT[f] = fmaf(xk, sWroot[k*HID_F + f], accT[f]);
        }
    }

    float4* yr = reinterpret_cast<float4*>(Y + (size_t)n * HID_F);
    float4* pr = reinterpret_cast<float4*>(P + (size_t)n * HID_F);
    #pragma unroll
    for (int q = 0; q < HID_F / 4; ++q) {
        yr[q] = make_float4(accR[4*q], accR[4*q+1], accR[4*q+2], accR[4*q+3]);
        pr[q] = make_float4(accT[4*q], accT[4*q+1], accT[4*q+2], accT[4*q+3]);
    }
}

// -------- Layer-2 node transform (in place): h=tanh(P); Y=h@Wrel; P=h@Wroot+b --
__global__ __launch_bounds__(256) void k3_lin16(
    float* __restrict__ Y, float* __restrict__ P,
    const float* __restrict__ Wrel, const float* __restrict__ b,
    const float* __restrict__ Wroot)
{
    __shared__ float sWrel[HID_F * HID_F];
    __shared__ float sWroot[HID_F * HID_F];
    __shared__ float sb[HID_F];
    if (threadIdx.x < HID_F * HID_F) {
        sWrel[threadIdx.x]  = Wrel[threadIdx.x];
        sWroot[threadIdx.x] = Wroot[threadIdx.x];
    }
    if (threadIdx.x < HID_F) sb[threadIdx.x] = b[threadIdx.x];
    __syncthreads();

    int n = blockIdx.x * 256 + threadIdx.x;
    if (n >= N_NODES) return;

    float h[HID_F];
    float4* pr = reinterpret_cast<float4*>(P + (size_t)n * HID_F);
    #pragma unroll
    for (int q = 0; q < HID_F / 4; ++q) {
        float4 t = pr[q];
        h[4*q+0] = tanhf(t.x); h[4*q+1] = tanhf(t.y);
        h[4*q+2] = tanhf(t.z); h[4*q+3] = tanhf(t.w);
    }

    float accR[HID_F], accT[HID_F];
    #pragma unroll
    for (int f = 0; f < HID_F; ++f) { accR[f] = 0.0f; accT[f] = sb[f]; }

    #pragma unroll
    for (int k = 0; k < HID_F; ++k) {
        float hk = h[k];
        #pragma unroll
        for (int f = 0; f < HID_F; ++f) {
            accR[f] = fmaf(hk, sWrel[k*HID_F + f], accR[f]);
            accT[f] = fmaf(hk, sWroot[k*HID_F + f], accT[f]);
        }
    }

    float4* yr = reinterpret_cast<float4*>(Y + (size_t)n * HID_F);
    #pragma unroll
    for (int q = 0; q < HID_F / 4; ++q) {
        yr[q] = make_float4(accR[4*q], accR[4*q+1], accR[4*q+2], accR[4*q+3]);
        pr[q] = make_float4(accT[4*q], accT[4*q+1], accT[4*q+2], accT[4*q+3]);
    }
}

// -------- Layer-3 prep: Y = tanh(P) (=h2), P = 0 (agg accumulator) ------------
__global__ __launch_bounds__(256) void k5_tanh_zero(
    float* __restrict__ P, float* __restrict__ Y)
{
    int n = blockIdx.x * 256 + threadIdx.x;
    if (n >= N_NODES) return;
    float4* pr = reinterpret_cast<float4*>(P + (size_t)n * HID_F);
    float4* yr = reinterpret_cast<float4*>(Y + (size_t)n * HID_F);
    #pragma unroll
    for (int q = 0; q < HID_F / 4; ++q) {
        float4 t = pr[q];
        yr[q] = make_float4(tanhf(t.x), tanhf(t.y), tanhf(t.z), tanhf(t.w));
        pr[q] = make_float4(0.f, 0.f, 0.f, 0.f);
    }
}

// -------- Output: out = P(agg)@W2_rel + b2 + Y(h2)@W2_root --------------------
__global__ __launch_bounds__(256) void k7_out(
    const float* __restrict__ P, const float* __restrict__ Y,
    const float* __restrict__ Wrel, const float* __restrict__ b,
    const float* __restrict__ Wroot, float* __restrict__ out)
{
    __shared__ float sWrel[HID_F * OUT_F];
    __shared__ float sWroot[HID_F * OUT_F];
    __shared__ float sb[OUT_F];
    for (int i = threadIdx.x; i < HID_F * OUT_F; i += 256) {
        sWrel[i]  = Wrel[i];
        sWroot[i] = Wroot[i];
    }
    if (threadIdx.x < OUT_F) sb[threadIdx.x] = b[threadIdx.x];
    __syncthreads();

    int n = blockIdx.x * 256 + threadIdx.x;
    if (n >= N_NODES) return;

    float agg[HID_F], h[HID_F];
    const float4* pr = reinterpret_cast<const float4*>(P + (size_t)n * HID_F);
    const float4* yr = reinterpret_cast<const float4*>(Y + (size_t)n * HID_F);
    #pragma unroll
    for (int q = 0; q < HID_F / 4; ++q) {
        float4 a = pr[q], hh = yr[q];
        agg[4*q+0] = a.x; agg[4*q+1] = a.y; agg[4*q+2] = a.z; agg[4*q+3] = a.w;
        h[4*q+0] = hh.x;  h[4*q+1] = hh.y;  h[4*q+2] = hh.z;  h[4*q+3] = hh.w;
    }

    float acc[OUT_F];
    #pragma unroll
    for (int j = 0; j < OUT_F; ++j) acc[j] = sb[j];

    #pragma unroll 2
    for (int f = 0; f < HID_F; ++f) {
        float a = agg[f], hh = h[f];
        #pragma unroll
        for (int j = 0; j < OUT_F; ++j) {
            acc[j] = fmaf(a,  sWrel[f*OUT_F + j], acc[j]);
            acc[j] = fmaf(hh, sWroot[f*OUT_F + j], acc[j]);
        }
    }

    float4* orow = reinterpret_cast<float4*>(out + (size_t)n * OUT_F);
    #pragma unroll
    for (int q = 0; q < OUT_F / 4; ++q) {
        orow[q] = make_float4(acc[4*q], acc[4*q+1], acc[4*q+2], acc[4*q+3]);
    }
}

extern "C" void kernel_launch(void* const* d_in, const int* in_sizes, int n_in,
                              void* d_out, int out_size, void* d_ws, size_t ws_size,
                              hipStream_t stream)
{
    const float* x        = (const float*)d_in[0];
    const int*   ei       = (const int*)d_in[1];
    const float* W1_rel   = (const float*)d_in[2];
    const float* b1       = (const float*)d_in[3];
    const float* W1_root  = (const float*)d_in[4];
    const float* W1b_rel  = (const float*)d_in[5];
    const float* b1b      = (const float*)d_in[6];
    const float* W1b_root = (const float*)d_in[7];
    const float* W2_rel   = (const float*)d_in[8];
    const float* b2       = (const float*)d_in[9];
    const float* W2_root  = (const float*)d_in[10];
    float* out = (float*)d_out;

    const int* src = ei;            // edge_index[0]
    const int* dst = ei + N_EDGES;  // edge_index[1]

    // Workspace layout (~19.6 MB)
    float* Y   = (float*)d_ws;                      // [N,16]
    float* P   = Y + (size_t)N_NODES * HID_F;       // [N,16]
    int* off   = (int*)(P + (size_t)N_NODES * HID_F); // [N] (ends after fill)
    int* csr   = off + N_NODES;                     // [E]
    int* blks  = csr + N_EDGES;                     // [512]

    const int nb_n = (N_NODES + 255) / 256;
    const int nb_e = (N_EDGES + 255) / 256;
    const int nb_g = (N_NODES * HID_F + 255) / 256;

    // ---- CSR build (once per call, reused by all 3 layers) ----
    k_zero_deg<<<nb_n, 256, 0, stream>>>(off);
    k_hist<<<nb_e, 256, 0, stream>>>(dst, off);
    k_scan_block<<<NB_SCAN, 256, 0, stream>>>(off, blks);
    k_scan_sums<<<1, 512, 0, stream>>>(blks);
    k_scan_add<<<NB_SCAN, 256, 0, stream>>>(off, blks);
    k_fill<<<nb_e, 256, 0, stream>>>(src, dst, off, csr);

    // ---- Layer 1 ----
    k1_lin48<<<nb_n, 256, 0, stream>>>(x, W1_rel, b1, W1_root, Y, P);
    k_gather<<<nb_g, 256, 0, stream>>>(off, csr, Y, P);
    // ---- Layer 2 ----
    k3_lin16<<<nb_n, 256, 0, stream>>>(Y, P, W1b_rel, b1b, W1b_root);
    k_gather<<<nb_g, 256, 0, stream>>>(off, csr, Y, P);
    // ---- Layer 3 ----
    k5_tanh_zero<<<nb_n, 256, 0, stream>>>(P, Y);
    k_gather<<<nb_g, 256, 0, stream>>>(off, csr, Y, P);
    k7_out<<<nb_n, 256, 0, stream>>>(P, Y, W2_rel, b2, W2_root, out);
}

// Round 3
// 247.833 us; speedup vs baseline: 15.9707x; 1.5184x over previous
//
#include <hip/hip_runtime.h>
#include <cmath>

#define N_NODES 100000
#define N_EDGES 1600000
#define IN_F 48
#define HID_F 16
#define OUT_F 60

#define BKT 256                                  // nodes per coarse bucket
#define NBKT ((N_NODES + BKT - 1) / BKT)         // 391
#define P3_EPB 8192                              // edges per partition block
#define NB_P3 ((N_EDGES + P3_EPB - 1) / P3_EPB)  // 196

// ---------------- CSR build: two-level counting sort --------------------------
__global__ __launch_bounds__(512) void k_zero_b(int* __restrict__ bcnt)
{
    if (threadIdx.x < NBKT) bcnt[threadIdx.x] = 0;
}

// Coarse histogram over 391 buckets (LDS-staged).
__global__ __launch_bounds__(256) void k_bhist(
    const int* __restrict__ dst, int* __restrict__ bcnt)
{
    __shared__ int h[NBKT];
    for (int i = threadIdx.x; i < NBKT; i += 256) h[i] = 0;
    __syncthreads();
    int base = blockIdx.x * 2048;
    #pragma unroll
    for (int i = 0; i < 8; ++i) {
        int e = base + i * 256 + threadIdx.x;
        if (e < N_EDGES) atomicAdd(&h[dst[e] >> 8], 1);
    }
    __syncthreads();
    for (int i = threadIdx.x; i < NBKT; i += 256)
        if (h[i]) atomicAdd(&bcnt[i], h[i]);
}

// Exclusive scan of bucket counts -> base[] (NBKT+1 entries) and cursor[].
__global__ __launch_bounds__(512) void k_bscan(
    const int* __restrict__ bcnt, int* __restrict__ base, int* __restrict__ cursor)
{
    __shared__ int tmp[512];
    int v = (threadIdx.x < NBKT) ? bcnt[threadIdx.x] : 0;
    tmp[threadIdx.x] = v;
    __syncthreads();
    #pragma unroll
    for (int ofs = 1; ofs < 512; ofs <<= 1) {
        int a = (threadIdx.x >= ofs) ? tmp[threadIdx.x - ofs] : 0;
        __syncthreads();
        tmp[threadIdx.x] += a;
        __syncthreads();
    }
    if (threadIdx.x < NBKT) {
        int ex = tmp[threadIdx.x] - v;
        base[threadIdx.x] = ex;
        cursor[threadIdx.x] = ex;
    }
    if (threadIdx.x == 0) base[NBKT] = N_EDGES;
}

// Partition edges into buckets; packed word = (src << 8) | dst_local.
// One cursor atomic per (block,bucket); writes are runs of ~21 words.
__global__ __launch_bounds__(256) void k_partition(
    const int* __restrict__ src, const int* __restrict__ dst,
    int* __restrict__ cursor, unsigned int* __restrict__ pk)
{
    __shared__ int cnt[NBKT];
    __shared__ int bb[NBKT];
    for (int i = threadIdx.x; i < NBKT; i += 256) cnt[i] = 0;
    __syncthreads();
    int e0 = blockIdx.x * P3_EPB;
    #pragma unroll 4
    for (int i = 0; i < 32; ++i) {
        int e = e0 + i * 256 + threadIdx.x;
        if (e < N_EDGES) atomicAdd(&cnt[dst[e] >> 8], 1);
    }
    __syncthreads();
    for (int i = threadIdx.x; i < NBKT; i += 256) {
        int c = cnt[i];
        bb[i] = c ? atomicAdd(&cursor[i], c) : 0;
        cnt[i] = 0;
    }
    __syncthreads();
    #pragma unroll 4
    for (int i = 0; i < 32; ++i) {
        int e = e0 + i * 256 + threadIdx.x;
        if (e < N_EDGES) {
            int d = dst[e];
            int b = d >> 8;
            int r = atomicAdd(&cnt[b], 1);
            pk[bb[b] + r] = ((unsigned int)src[e] << 8) | (unsigned int)(d & 255);
        }
    }
}

// One block per bucket: exact per-node CSR via LDS hist + scan + bump cursors.
// csr writes land in a 16KB hot window -> coalesced write-back.
__global__ __launch_bounds__(256) void k_bucket_csr(
    const int* __restrict__ base, const unsigned int* __restrict__ pk,
    int* __restrict__ off_end, int* __restrict__ csr)
{
    __shared__ int hist[BKT];
    __shared__ int tmp[BKT];
    __shared__ int cur[BKT];
    int b = blockIdx.x;
    int e0 = base[b], e1 = base[b + 1];
    hist[threadIdx.x] = 0;
    __syncthreads();
    for (int e = e0 + threadIdx.x; e < e1; e += 256)
        atomicAdd(&hist[pk[e] & 255u], 1);
    __syncthreads();
    int v = hist[threadIdx.x];
    tmp[threadIdx.x] = v;
    __syncthreads();
    #pragma unroll
    for (int ofs = 1; ofs < 256; ofs <<= 1) {
        int a = (threadIdx.x >= ofs) ? tmp[threadIdx.x - ofs] : 0;
        __syncthreads();
        tmp[threadIdx.x] += a;
        __syncthreads();
    }
    int incl = tmp[threadIdx.x];
    cur[threadIdx.x] = e0 + incl - v;            // segment start
    int n = b * BKT + threadIdx.x;
    if (n < N_NODES) off_end[n] = e0 + incl;     // segment end
    __syncthreads();
    for (int e = e0 + threadIdx.x; e < e1; e += 256) {
        unsigned int p = pk[e];
        int dl = (int)(p & 255u);
        int pos = atomicAdd(&cur[dl], 1);
        csr[pos] = (int)(p >> 8);
    }
}

// ---------------- Gather: P[n] += sum_{e in in(n)} Y[src[e]] ------------------
__global__ __launch_bounds__(256) void k_gather(
    const int* __restrict__ off_end, const int* __restrict__ csr_src,
    const float* __restrict__ Y, float* __restrict__ P)
{
    int t = blockIdx.x * 256 + threadIdx.x;
    int n = t >> 4;
    int lane = t & 15;
    if (n >= N_NODES) return;
    int e0 = (n == 0) ? 0 : off_end[n - 1];
    int e1 = off_end[n];

    float acc0 = 0.f, acc1 = 0.f;
    int e = e0;
    for (; e + 1 < e1; e += 2) {
        int s0 = csr_src[e];
        int s1 = csr_src[e + 1];
        acc0 += Y[(size_t)s0 * HID_F + lane];
        acc1 += Y[(size_t)s1 * HID_F + lane];
    }
    if (e < e1) acc0 += Y[(size_t)csr_src[e] * HID_F + lane];
    P[(size_t)n * HID_F + lane] += acc0 + acc1;
}

// ---------------- Layer-1 node transform: Y = x@W1_rel, P = x@W1_root + b1 ----
__global__ __launch_bounds__(256) void k1_lin48(
    const float* __restrict__ x, const float* __restrict__ Wrel,
    const float* __restrict__ b, const float* __restrict__ Wroot,
    float* __restrict__ Y, float* __restrict__ P)
{
    __shared__ float sWrel[IN_F * HID_F];
    __shared__ float sWroot[IN_F * HID_F];
    __shared__ float sb[HID_F];
    for (int i = threadIdx.x; i < IN_F * HID_F; i += 256) {
        sWrel[i]  = Wrel[i];
        sWroot[i] = Wroot[i];
    }
    if (threadIdx.x < HID_F) sb[threadIdx.x] = b[threadIdx.x];
    __syncthreads();

    int n = blockIdx.x * 256 + threadIdx.x;
    if (n >= N_NODES) return;

    float xv[IN_F];
    const float4* xr = reinterpret_cast<const float4*>(x + (size_t)n * IN_F);
    #pragma unroll
    for (int i = 0; i < IN_F / 4; ++i) {
        float4 t = xr[i];
        xv[4*i+0] = t.x; xv[4*i+1] = t.y; xv[4*i+2] = t.z; xv[4*i+3] = t.w;
    }

    float accR[HID_F], accT[HID_F];
    #pragma unroll
    for (int f = 0; f < HID_F; ++f) { accR[f] = 0.0f; accT[f] = sb[f]; }

    #pragma unroll 6
    for (int k = 0; k < IN_F; ++k) {
        float xk = xv[k];
        #pragma unroll
        for (int f = 0; f < HID_F; ++f) {
            accR[f] = fmaf(xk, sWrel[k*HID_F + f], accR[f]);
            accT[f] = fmaf(xk, sWroot[k*HID_F + f], accT[f]);
        }
    }

    float4* yr = reinterpret_cast<float4*>(Y + (size_t)n * HID_F);
    float4* pr = reinterpret_cast<float4*>(P + (size_t)n * HID_F);
    #pragma unroll
    for (int q = 0; q < HID_F / 4; ++q) {
        yr[q] = make_float4(accR[4*q], accR[4*q+1], accR[4*q+2], accR[4*q+3]);
        pr[q] = make_float4(accT[4*q], accT[4*q+1], accT[4*q+2], accT[4*q+3]);
    }
}

// -------- Layer-2 node transform (in place): h=tanh(P); Y=h@Wrel; P=h@Wroot+b --
__global__ __launch_bounds__(256) void k3_lin16(
    float* __restrict__ Y, float* __restrict__ P,
    const float* __restrict__ Wrel, const float* __restrict__ b,
    const float* __restrict__ Wroot)
{
    __shared__ float sWrel[HID_F * HID_F];
    __shared__ float sWroot[HID_F * HID_F];
    __shared__ float sb[HID_F];
    if (threadIdx.x < HID_F * HID_F) {
        sWrel[threadIdx.x]  = Wrel[threadIdx.x];
        sWroot[threadIdx.x] = Wroot[threadIdx.x];
    }
    if (threadIdx.x < HID_F) sb[threadIdx.x] = b[threadIdx.x];
    __syncthreads();

    int n = blockIdx.x * 256 + threadIdx.x;
    if (n >= N_NODES) return;

    float h[HID_F];
    float4* pr = reinterpret_cast<float4*>(P + (size_t)n * HID_F);
    #pragma unroll
    for (int q = 0; q < HID_F / 4; ++q) {
        float4 t = pr[q];
        h[4*q+0] = tanhf(t.x); h[4*q+1] = tanhf(t.y);
        h[4*q+2] = tanhf(t.z); h[4*q+3] = tanhf(t.w);
    }

    float accR[HID_F], accT[HID_F];
    #pragma unroll
    for (int f = 0; f < HID_F; ++f) { accR[f] = 0.0f; accT[f] = sb[f]; }

    #pragma unroll
    for (int k = 0; k < HID_F; ++k) {
        float hk = h[k];
        #pragma unroll
        for (int f = 0; f < HID_F; ++f) {
            accR[f] = fmaf(hk, sWrel[k*HID_F + f], accR[f]);
            accT[f] = fmaf(hk, sWroot[k*HID_F + f], accT[f]);
        }
    }

    float4* yr = reinterpret_cast<float4*>(Y + (size_t)n * HID_F);
    #pragma unroll
    for (int q = 0; q < HID_F / 4; ++q) {
        yr[q] = make_float4(accR[4*q], accR[4*q+1], accR[4*q+2], accR[4*q+3]);
        pr[q] = make_float4(accT[4*q], accT[4*q+1], accT[4*q+2], accT[4*q+3]);
    }
}

// -------- Layer-3 prep: Y = tanh(P) (=h2), P = 0 (agg accumulator) ------------
__global__ __launch_bounds__(256) void k5_tanh_zero(
    float* __restrict__ P, float* __restrict__ Y)
{
    int n = blockIdx.x * 256 + threadIdx.x;
    if (n >= N_NODES) return;
    float4* pr = reinterpret_cast<float4*>(P + (size_t)n * HID_F);
    float4* yr = reinterpret_cast<float4*>(Y + (size_t)n * HID_F);
    #pragma unroll
    for (int q = 0; q < HID_F / 4; ++q) {
        float4 t = pr[q];
        yr[q] = make_float4(tanhf(t.x), tanhf(t.y), tanhf(t.z), tanhf(t.w));
        pr[q] = make_float4(0.f, 0.f, 0.f, 0.f);
    }
}

// -------- Output: out = P(agg)@W2_rel + b2 + Y(h2)@W2_root --------------------
__global__ __launch_bounds__(256) void k7_out(
    const float* __restrict__ P, const float* __restrict__ Y,
    const float* __restrict__ Wrel, const float* __restrict__ b,
    const float* __restrict__ Wroot, float* __restrict__ out)
{
    __shared__ float sWrel[HID_F * OUT_F];
    __shared__ float sWroot[HID_F * OUT_F];
    __shared__ float sb[OUT_F];
    for (int i = threadIdx.x; i < HID_F * OUT_F; i += 256) {
        sWrel[i]  = Wrel[i];
        sWroot[i] = Wroot[i];
    }
    if (threadIdx.x < OUT_F) sb[threadIdx.x] = b[threadIdx.x];
    __syncthreads();

    int n = blockIdx.x * 256 + threadIdx.x;
    if (n >= N_NODES) return;

    float agg[HID_F], h[HID_F];
    const float4* pr = reinterpret_cast<const float4*>(P + (size_t)n * HID_F);
    const float4* yr = reinterpret_cast<const float4*>(Y + (size_t)n * HID_F);
    #pragma unroll
    for (int q = 0; q < HID_F / 4; ++q) {
        float4 a = pr[q], hh = yr[q];
        agg[4*q+0] = a.x; agg[4*q+1] = a.y; agg[4*q+2] = a.z; agg[4*q+3] = a.w;
        h[4*q+0] = hh.x;  h[4*q+1] = hh.y;  h[4*q+2] = hh.z;  h[4*q+3] = hh.w;
    }

    float acc[OUT_F];
    #pragma unroll
    for (int j = 0; j < OUT_F; ++j) acc[j] = sb[j];

    #pragma unroll 2
    for (int f = 0; f < HID_F; ++f) {
        float a = agg[f], hh = h[f];
        #pragma unroll
        for (int j = 0; j < OUT_F; ++j) {
            acc[j] = fmaf(a,  sWrel[f*OUT_F + j], acc[j]);
            acc[j] = fmaf(hh, sWroot[f*OUT_F + j], acc[j]);
        }
    }

    float4* orow = reinterpret_cast<float4*>(out + (size_t)n * OUT_F);
    #pragma unroll
    for (int q = 0; q < OUT_F / 4; ++q) {
        orow[q] = make_float4(acc[4*q], acc[4*q+1], acc[4*q+2], acc[4*q+3]);
    }
}

extern "C" void kernel_launch(void* const* d_in, const int* in_sizes, int n_in,
                              void* d_out, int out_size, void* d_ws, size_t ws_size,
                              hipStream_t stream)
{
    const float* x        = (const float*)d_in[0];
    const int*   ei       = (const int*)d_in[1];
    const float* W1_rel   = (const float*)d_in[2];
    const float* b1       = (const float*)d_in[3];
    const float* W1_root  = (const float*)d_in[4];
    const float* W1b_rel  = (const float*)d_in[5];
    const float* b1b      = (const float*)d_in[6];
    const float* W1b_root = (const float*)d_in[7];
    const float* W2_rel   = (const float*)d_in[8];
    const float* b2       = (const float*)d_in[9];
    const float* W2_root  = (const float*)d_in[10];
    float* out = (float*)d_out;

    const int* src = ei;            // edge_index[0]
    const int* dst = ei + N_EDGES;  // edge_index[1]

    // Workspace (~19.6 MB). pk aliases d_out's first 6.4 MB (consumed before k7).
    float* Y     = (float*)d_ws;                          // [N,16]
    float* P     = Y + (size_t)N_NODES * HID_F;           // [N,16]
    int* csr     = (int*)(P + (size_t)N_NODES * HID_F);   // [E]
    int* off_end = csr + N_EDGES;                         // [N]
    int* bcnt    = off_end + N_NODES;                     // [NBKT]
    int* base    = bcnt + NBKT;                           // [NBKT+1]
    int* cursor  = base + NBKT + 1;                       // [NBKT]
    unsigned int* pk = (unsigned int*)d_out;              // [E] scratch, then overwritten

    const int nb_n = (N_NODES + 255) / 256;
    const int nb_g = (N_NODES * HID_F + 255) / 256;
    const int nb_h = (N_EDGES + 2047) / 2048;

    // ---- CSR build: two-level counting sort ----
    k_zero_b<<<1, 512, 0, stream>>>(bcnt);
    k_bhist<<<nb_h, 256, 0, stream>>>(dst, bcnt);
    k_bscan<<<1, 512, 0, stream>>>(bcnt, base, cursor);
    k_partition<<<NB_P3, 256, 0, stream>>>(src, dst, cursor, pk);
    k_bucket_csr<<<NBKT, 256, 0, stream>>>(base, pk, off_end, csr);

    // ---- Layer 1 ----
    k1_lin48<<<nb_n, 256, 0, stream>>>(x, W1_rel, b1, W1_root, Y, P);
    k_gather<<<nb_g, 256, 0, stream>>>(off_end, csr, Y, P);
    // ---- Layer 2 ----
    k3_lin16<<<nb_n, 256, 0, stream>>>(Y, P, W1b_rel, b1b, W1b_root);
    k_gather<<<nb_g, 256, 0, stream>>>(off_end, csr, Y, P);
    // ---- Layer 3 ----
    k5_tanh_zero<<<nb_n, 256, 0, stream>>>(P, Y);
    k_gather<<<nb_g, 256, 0, stream>>>(off_end, csr, Y, P);
    k7_out<<<nb_n, 256, 0, stream>>>(P, Y, W2_rel, b2, W2_root, out);
}